// Round 4
// baseline (3997.593 us; speedup 1.0000x reference)
//
#include <hip/hip_runtime.h>
#include <math.h>

#define NB 256
#define TT 64
#define DD 1024
#define HH 1024
#define FOURH 4096
#define KTOT 3072
#define KT96 96                   // K-tiles of 32
#define P1 (NB * FOURH)           // one partial plane (f32 elems)

#define AF_LVL 786432ull          // 16 rt * 96 kt * 512
#define BF_LVL 12582912ull        // 256 ct * 96 kt * 512
#define SPLIT_SCALE 2048.0f
#define INV_SPLIT (1.0f / 2048.0f)

typedef _Float16 f16x8 __attribute__((ext_vector_type(8)));
typedef float f32x4 __attribute__((ext_vector_type(4)));

__device__ __forceinline__ unsigned short f2h(float f) {
    _Float16 h = (_Float16)f;
    unsigned short u;
    __builtin_memcpy(&u, &h, 2);
    return u;
}
__device__ __forceinline__ float h2f(unsigned short u) {
    _Float16 h;
    __builtin_memcpy(&h, &u, 2);
    return (float)h;
}
// 2-way fp16 split; lo pre-scaled by 2^11 to stay out of subnormal range
__device__ __forceinline__ void split2(float f, unsigned short& hi, unsigned short& lo) {
    hi = f2h(f);
    lo = f2h((f - h2f(hi)) * SPLIT_SCALE);
}

// fragment layout (empirically validated R2/R3): lane l holds [row=l&15][k=kt*32+(l>>4)*8+0..7]
__device__ __forceinline__ size_t aoff(int lvl, int rt, int kt, int lane) {
    return ((size_t)((lvl * 16 + rt) * KT96 + kt) * 64 + lane) * 8;
}
__device__ __forceinline__ size_t boff(int lvl, int ct, int kt, int lane) {
    return ((size_t)((lvl * 256 + ct) * KT96 + kt) * 64 + lane) * 8;
}

__device__ __forceinline__ void write_frag8(unsigned short* __restrict__ Af, int n, int k8, const float* v) {
    int rt = n >> 4, kt = k8 >> 5;
    int lane = (n & 15) + 16 * ((k8 >> 3) & 3);
    unsigned short s[8][2];
#pragma unroll
    for (int i = 0; i < 8; ++i) split2(v[i], s[i][0], s[i][1]);
#pragma unroll
    for (int lvl = 0; lvl < 2; ++lvl) {
        uint4 p;
        p.x = (unsigned)s[0][lvl] | ((unsigned)s[1][lvl] << 16);
        p.y = (unsigned)s[2][lvl] | ((unsigned)s[3][lvl] << 16);
        p.z = (unsigned)s[4][lvl] | ((unsigned)s[5][lvl] << 16);
        p.w = (unsigned)s[6][lvl] | ((unsigned)s[7][lvl] << 16);
        *reinterpret_cast<uint4*>(Af + aoff(lvl, rt, kt, lane)) = p;
    }
}

// ---------------- weight split: W[k][j] f32 -> B-fragment order (2-level f16) ----------------
__global__ __launch_bounds__(256) void wsplit_kernel(const float* __restrict__ Wx,
                                                     const float* __restrict__ Wh,
                                                     const float* __restrict__ Wattn,
                                                     unsigned short* __restrict__ Bf) {
    __shared__ float tile[32][33];
    int k0 = blockIdx.x * 32, j0 = blockIdx.y * 32;
    int t = threadIdx.x;
    int rl = t >> 3, c4 = (t & 7) * 4;
    int seg = k0 >> 10;
    const float* W = (seg == 0) ? Wx : (seg == 1) ? Wh : Wattn;
    const float4 v = *reinterpret_cast<const float4*>(W + (size_t)((k0 & 1023) + rl) * FOURH + j0 + c4);
    tile[rl][c4 + 0] = v.x; tile[rl][c4 + 1] = v.y; tile[rl][c4 + 2] = v.z; tile[rl][c4 + 3] = v.w;
    __syncthreads();
    int jl = t >> 3, k4 = (t & 7) * 4;
    unsigned short s[4][2];
#pragma unroll
    for (int i = 0; i < 4; ++i) split2(tile[k4 + i][jl], s[i][0], s[i][1]);
    int j = j0 + jl;
    int kg = k0 + k4;
    int ct = j >> 4, kt = kg >> 5;
    int lane = (j & 15) + 16 * ((kg >> 3) & 3);
    int sub = kg & 7;   // 0 or 4
#pragma unroll
    for (int lvl = 0; lvl < 2; ++lvl) {
        uint2 p;
        p.x = (unsigned)s[0][lvl] | ((unsigned)s[1][lvl] << 16);
        p.y = (unsigned)s[2][lvl] | ((unsigned)s[3][lvl] << 16);
        *reinterpret_cast<uint2*>(Bf + boff(lvl, ct, kt, lane) + sub) = p;
    }
}

// ---------------- shared device phases ----------------
__device__ __forceinline__ void attn_phase(const float* __restrict__ A, int n, int tid,
                                           const float* hsh, float* ash, float* red2) {
    int lane = tid & 63, wave = tid >> 6;
    const float* An = A + (size_t)n * HH * 16;
    float areg[4][16];
    float part[16];
#pragma unroll
    for (int k = 0; k < 16; ++k) part[k] = 0.f;
#pragma unroll
    for (int i = 0; i < 4; ++i) {
        int hh = tid + i * 256;
        float hv = hsh[hh];
        const float* ap = An + (size_t)hh * 16;
#pragma unroll
        for (int k = 0; k < 16; ++k) {
            float av = ap[k];
            areg[i][k] = av;
            part[k] += hv * av;
        }
    }
#pragma unroll
    for (int k = 0; k < 16; ++k) {
        float v = part[k];
#pragma unroll
        for (int off = 32; off > 0; off >>= 1) v += __shfl_down(v, off);
        if (lane == 0) red2[wave * 16 + k] = v;
    }
    __syncthreads();
    float w[16];
    float mx = -1e30f;
#pragma unroll
    for (int k = 0; k < 16; ++k) {
        float s = (red2[k] + red2[16 + k] + red2[32 + k] + red2[48 + k]) * 0.03125f;
        w[k] = s;
        mx = fmaxf(mx, s);
    }
    float sum = 0.f;
#pragma unroll
    for (int k = 0; k < 16; ++k) {
        w[k] = expf(w[k] - mx);
        sum += w[k];
    }
    float inv = 1.0f / sum;
#pragma unroll
    for (int k = 0; k < 16; ++k) w[k] *= inv;
#pragma unroll
    for (int i = 0; i < 4; ++i) {
        float s = 0.f;
#pragma unroll
        for (int k = 0; k < 16; ++k) s += areg[i][k] * w[k];
        ash[tid + i * 256] = s;
    }
}

__device__ __forceinline__ void write_state_frags(unsigned short* __restrict__ Af,
                                                  const float* __restrict__ x,
                                                  const float* hsh, const float* ash,
                                                  int n, int tnext, int tid) {
    if (tid >= 128) return;
    int k8 = tid * 8;
    float v[8];
#pragma unroll
    for (int i = 0; i < 8; ++i) v[i] = hsh[k8 + i];
    write_frag8(Af, n, 1024 + k8, v);
#pragma unroll
    for (int i = 0; i < 8; ++i) v[i] = ash[k8 + i];
    write_frag8(Af, n, 2048 + k8, v);
    if (tnext < TT) {
        const float4* xp = reinterpret_cast<const float4*>(x + ((size_t)n * TT + tnext) * DD + k8);
        float4 x0 = xp[0], x1 = xp[1];
        v[0] = x0.x; v[1] = x0.y; v[2] = x0.z; v[3] = x0.w;
        v[4] = x1.x; v[5] = x1.y; v[6] = x1.z; v[7] = x1.w;
        write_frag8(Af, n, k8, v);
    }
}

// ---------------- init ----------------
__global__ __launch_bounds__(256) void initk(const float* __restrict__ A,
                                             const float* __restrict__ x,
                                             float* __restrict__ c,
                                             unsigned short* __restrict__ Af) {
    int n = blockIdx.x, tid = threadIdx.x;
    __shared__ float hsh[HH], ash[HH];
    __shared__ float red2[64];
#pragma unroll
    for (int i = 0; i < 4; ++i) {
        int hh = tid + i * 256;
        const float* ap = A + ((size_t)n * HH + hh) * 16;
        float s = 0.f;
#pragma unroll
        for (int k = 0; k < 16; ++k) s += ap[k];
        s *= (1.0f / 16.0f);
        c[(size_t)n * HH + hh] = s;
        hsh[hh] = s;
    }
    __syncthreads();
    attn_phase(A, n, tid, hsh, ash, red2);
    __syncthreads();
    write_state_frags(Af, x, hsh, ash, n, 0, tid);
}

// ---------------- MFMA GEMM: fragment-direct, fp16 2-level, reg double-buffer ----------------
// grid 256 = z2 x colb64 x rowb2; 512 thr = 8 waves (wm2 x wn2 x wk2)
#define LOAD_FRAGS(buf, kt)                                                                   \
    {                                                                                         \
        _Pragma("unroll") for (int lvl = 0; lvl < 2; ++lvl) {                                 \
            _Pragma("unroll") for (int i = 0; i < 4; ++i)                                     \
                FA[buf][lvl][i] = *reinterpret_cast<const uint4*>(paBase[lvl][i] + (size_t)(kt) * 512); \
            _Pragma("unroll") for (int j = 0; j < 2; ++j)                                     \
                FB[buf][lvl][j] = *reinterpret_cast<const uint4*>(pbBase[lvl][j] + (size_t)(kt) * 512); \
        }                                                                                     \
    }

#define DO_MFMA(buf)                                                                          \
    {                                                                                         \
        _Pragma("unroll") for (int mi = 0; mi < 4; ++mi) {                                    \
            f16x8 a0 = __builtin_bit_cast(f16x8, FA[buf][0][mi]);                             \
            f16x8 a1 = __builtin_bit_cast(f16x8, FA[buf][1][mi]);                             \
            _Pragma("unroll") for (int ni = 0; ni < 2; ++ni) {                                \
                f16x8 b0 = __builtin_bit_cast(f16x8, FB[buf][0][ni]);                         \
                f16x8 b1 = __builtin_bit_cast(f16x8, FB[buf][1][ni]);                         \
                accH[mi][ni] = __builtin_amdgcn_mfma_f32_16x16x32_f16(a0, b0, accH[mi][ni], 0, 0, 0); \
                accM[mi][ni] = __builtin_amdgcn_mfma_f32_16x16x32_f16(a0, b1, accM[mi][ni], 0, 0, 0); \
                accM[mi][ni] = __builtin_amdgcn_mfma_f32_16x16x32_f16(a1, b0, accM[mi][ni], 0, 0, 0); \
            }                                                                                 \
        }                                                                                     \
    }

__global__ __launch_bounds__(512, 2) void gemm_mfma(const unsigned short* __restrict__ Af,
                                                    const unsigned short* __restrict__ Bf,
                                                    float* __restrict__ apart) {
    int tid = threadIdx.x;
    int l = tid & 63, w = tid >> 6;
    int wm = w & 1, wn = (w >> 1) & 1, wk = w >> 2;
    int wg = blockIdx.x;
    int id = (wg & 7) * 32 + (wg >> 3);   // XCD-chunked: each XCD gets 32 contiguous ids
    int rowb = id & 1, colb = (id >> 1) & 63, z = id >> 7;
    int rtb = rowb * 8 + wm * 4;          // 4 rt per wave (64 rows)
    int ctb = colb * 4 + wn * 2;          // 2 ct per wave (32 cols)
    int kt0 = z * 48 + wk * 24;           // 24 kt per wave

    const unsigned short* paBase[2][4];
    const unsigned short* pbBase[2][2];
#pragma unroll
    for (int lvl = 0; lvl < 2; ++lvl) {
#pragma unroll
        for (int i = 0; i < 4; ++i)
            paBase[lvl][i] = Af + ((size_t)((lvl * 16 + rtb + i) * KT96) * 64 + l) * 8;
#pragma unroll
        for (int j = 0; j < 2; ++j)
            pbBase[lvl][j] = Bf + ((size_t)((lvl * 256 + ctb + j) * KT96) * 64 + l) * 8;
    }

    f32x4 accH[4][2] = {};
    f32x4 accM[4][2] = {};
    uint4 FA[2][2][4];
    uint4 FB[2][2][2];

    LOAD_FRAGS(0, kt0)
    for (int ktt = 0; ktt < 24; ktt += 2) {
        LOAD_FRAGS(1, kt0 + ktt + 1)
        DO_MFMA(0)
        int nxt = (ktt + 2 < 24) ? (ktt + 2) : 0;   // last prefetch harmless
        LOAD_FRAGS(0, kt0 + nxt)
        DO_MFMA(1)
    }

    // combine hi + mid/2048, reduce across wk via LDS, write plane
    __shared__ float red[4][8][256];   // 32 KB
    int q = wm * 2 + wn;
    f32x4 comb[4][2];
#pragma unroll
    for (int mi = 0; mi < 4; ++mi)
#pragma unroll
        for (int ni = 0; ni < 2; ++ni)
#pragma unroll
            for (int r = 0; r < 4; ++r)
                comb[mi][ni][r] = accH[mi][ni][r] + accM[mi][ni][r] * INV_SPLIT;

    if (wk == 1) {
#pragma unroll
        for (int mi = 0; mi < 4; ++mi)
#pragma unroll
            for (int ni = 0; ni < 2; ++ni)
                *reinterpret_cast<f32x4*>(&red[q][mi * 2 + ni][l * 4]) = comb[mi][ni];
    }
    __syncthreads();
    if (wk == 0) {
        float* plane = apart + (size_t)z * P1;
#pragma unroll
        for (int mi = 0; mi < 4; ++mi) {
            int rbase = rowb * 128 + wm * 64 + mi * 16 + (l >> 4) * 4;
#pragma unroll
            for (int ni = 0; ni < 2; ++ni) {
                f32x4 o = *reinterpret_cast<f32x4*>(&red[q][mi * 2 + ni][l * 4]);
                int cg = colb * 64 + wn * 32 + ni * 16 + (l & 15);
#pragma unroll
                for (int r = 0; r < 4; ++r)
                    plane[(size_t)(rbase + r) * FOURH + cg] = comb[mi][ni][r] + o[r];
            }
        }
    }
}

// ---------------- pointwise: gates + LSTM + attn + frag writes ----------------
__global__ __launch_bounds__(256) void pointwise(const float* __restrict__ apart,
                                                 const float* __restrict__ bias,
                                                 const float* __restrict__ A,
                                                 const float* __restrict__ x,
                                                 float* __restrict__ c,
                                                 float* __restrict__ out,
                                                 unsigned short* __restrict__ Af, int t) {
    int n = blockIdx.x, tid = threadIdx.x;
    __shared__ float hsh[HH], ash[HH];
    __shared__ float red2[64];
    const float* ap = apart + (size_t)n * FOURH;
#pragma unroll
    for (int i = 0; i < 4; ++i) {
        int hh = i * 256 + tid;
        float g4[4];
#pragma unroll
        for (int g = 0; g < 4; ++g) {
            int j = g * 1024 + hh;
            g4[g] = bias[j] + ap[j] + ap[(size_t)P1 + j];
        }
        float ig = 1.f / (1.f + expf(-g4[0]));
        float fg = 1.f / (1.f + expf(-g4[1]));
        float og = 1.f / (1.f + expf(-g4[2]));
        float gg = tanhf(g4[3]);
        float cn = fg * c[(size_t)n * HH + hh] + ig * gg;
        float hn = og * tanhf(cn);
        c[(size_t)n * HH + hh] = cn;
        out[((size_t)n * TT + t) * HH + hh] = hn;
        hsh[hh] = hn;
    }
    __syncthreads();
    attn_phase(A, n, tid, hsh, ash, red2);
    __syncthreads();
    write_state_frags(Af, x, hsh, ash, n, t + 1, tid);
}

extern "C" void kernel_launch(void* const* d_in, const int* in_sizes, int n_in,
                              void* d_out, int out_size, void* d_ws, size_t ws_size,
                              hipStream_t stream) {
    const float* x     = (const float*)d_in[0];
    const float* A     = (const float*)d_in[1];
    const float* Wx    = (const float*)d_in[2];
    const float* Wh    = (const float*)d_in[3];
    const float* Wattn = (const float*)d_in[4];
    const float* b     = (const float*)d_in[5];
    float* out = (float*)d_out;

    unsigned short* Bf = (unsigned short*)d_ws;        // 2*BF_LVL f16 = 50.3 MB
    unsigned short* Af = Bf + 2 * BF_LVL;              // 2*AF_LVL f16 = 3.1 MB
    float* apart = (float*)(Af + 2 * AF_LVL);          // 2 * P1 f32 = 8 MB
    float* c = apart + 2 * (size_t)P1;                 // 1 MB

    wsplit_kernel<<<dim3(KTOT / 32, FOURH / 32), 256, 0, stream>>>(Wx, Wh, Wattn, Bf);
    initk<<<NB, 256, 0, stream>>>(A, x, c, Af);

    for (int t = 0; t < TT; ++t) {
        gemm_mfma<<<256, 512, 0, stream>>>(Af, Bf, apart);
        pointwise<<<NB, 256, 0, stream>>>(apart, b, A, x, c, out, Af, t);
    }
}

// Round 5
// 2840.430 us; speedup vs baseline: 1.4074x; 1.4074x over previous
//
#include <hip/hip_runtime.h>
#include <math.h>

#define NB 256
#define TT 64
#define DD 1024
#define HH 1024
#define FOURH 4096
#define KTOT 3072
#define KT16 192                  // K-tiles of 16
#define P1 (NB * FOURH)           // one partial plane (f32 elems)

#define AF_LVL 786432ull          // 8 mt * 192 kt * 512
#define BF_LVL 12582912ull        // 128 ct * 192 kt * 512
#define SPLIT_SCALE 2048.0f
#define INV_SPLIT (1.0f / 2048.0f)

typedef _Float16 f16x8 __attribute__((ext_vector_type(8)));
typedef float f32x4 __attribute__((ext_vector_type(4)));
typedef float f32x16 __attribute__((ext_vector_type(16)));

__device__ __forceinline__ unsigned short f2h(float f) {
    _Float16 h = (_Float16)f;
    unsigned short u;
    __builtin_memcpy(&u, &h, 2);
    return u;
}
__device__ __forceinline__ float h2f(unsigned short u) {
    _Float16 h;
    __builtin_memcpy(&h, &u, 2);
    return (float)h;
}
// 2-way fp16 split; lo pre-scaled by 2^11 to stay out of subnormal range
__device__ __forceinline__ void split2(float f, unsigned short& hi, unsigned short& lo) {
    hi = f2h(f);
    lo = f2h((f - h2f(hi)) * SPLIT_SCALE);
}

// 32x32x16 fragment layout: lane l holds [row/col = l&31][k = kt*16 + (l>>5)*8 + 0..7]
__device__ __forceinline__ size_t aoff(int lvl, int mt, int kt, int lane) {
    return ((size_t)((lvl * 8 + mt) * KT16 + kt) * 64 + lane) * 8;
}
__device__ __forceinline__ size_t boff(int lvl, int ct, int kt, int lane) {
    return ((size_t)((lvl * 128 + ct) * KT16 + kt) * 64 + lane) * 8;
}

__device__ __forceinline__ void write_frag8(unsigned short* __restrict__ Af, int n, int k8, const float* v) {
    int mt = n >> 5, kt = k8 >> 4;
    int lane = (n & 31) + 32 * ((k8 >> 3) & 1);
    unsigned short s[8][2];
#pragma unroll
    for (int i = 0; i < 8; ++i) split2(v[i], s[i][0], s[i][1]);
#pragma unroll
    for (int lvl = 0; lvl < 2; ++lvl) {
        uint4 p;
        p.x = (unsigned)s[0][lvl] | ((unsigned)s[1][lvl] << 16);
        p.y = (unsigned)s[2][lvl] | ((unsigned)s[3][lvl] << 16);
        p.z = (unsigned)s[4][lvl] | ((unsigned)s[5][lvl] << 16);
        p.w = (unsigned)s[6][lvl] | ((unsigned)s[7][lvl] << 16);
        *reinterpret_cast<uint4*>(Af + aoff(lvl, mt, kt, lane)) = p;
    }
}

// ---------------- weight split: W[k][j] f32 -> B-fragment order (2-level f16) ----------------
__global__ __launch_bounds__(256) void wsplit_kernel(const float* __restrict__ Wx,
                                                     const float* __restrict__ Wh,
                                                     const float* __restrict__ Wattn,
                                                     unsigned short* __restrict__ Bf) {
    __shared__ float tile[32][33];
    int k0 = blockIdx.x * 32, j0 = blockIdx.y * 32;
    int t = threadIdx.x;
    int rl = t >> 3, c4 = (t & 7) * 4;
    int seg = k0 >> 10;
    const float* W = (seg == 0) ? Wx : (seg == 1) ? Wh : Wattn;
    const float4 v = *reinterpret_cast<const float4*>(W + (size_t)((k0 & 1023) + rl) * FOURH + j0 + c4);
    tile[rl][c4 + 0] = v.x; tile[rl][c4 + 1] = v.y; tile[rl][c4 + 2] = v.z; tile[rl][c4 + 3] = v.w;
    __syncthreads();
    int jl = t >> 3, k4 = (t & 7) * 4;
    unsigned short s[4][2];
#pragma unroll
    for (int i = 0; i < 4; ++i) split2(tile[k4 + i][jl], s[i][0], s[i][1]);
    int j = j0 + jl;
    int kg = k0 + k4;
    int ct = j >> 5, kt = kg >> 4;
    int lane = (j & 31) + 32 * ((kg >> 3) & 1);
    int sub = kg & 7;   // 0 or 4
#pragma unroll
    for (int lvl = 0; lvl < 2; ++lvl) {
        uint2 p;
        p.x = (unsigned)s[0][lvl] | ((unsigned)s[1][lvl] << 16);
        p.y = (unsigned)s[2][lvl] | ((unsigned)s[3][lvl] << 16);
        *reinterpret_cast<uint2*>(Bf + boff(lvl, ct, kt, lane) + sub) = p;
    }
}

// ---------------- shared device phases ----------------
__device__ __forceinline__ void attn_phase(const float* __restrict__ A, int n, int tid,
                                           const float* hsh, float* ash, float* red2) {
    int lane = tid & 63, wave = tid >> 6;
    const float* An = A + (size_t)n * HH * 16;
    float areg[4][16];
    float part[16];
#pragma unroll
    for (int k = 0; k < 16; ++k) part[k] = 0.f;
#pragma unroll
    for (int i = 0; i < 4; ++i) {
        int hh = tid + i * 256;
        float hv = hsh[hh];
        const float* ap = An + (size_t)hh * 16;
#pragma unroll
        for (int k = 0; k < 16; ++k) {
            float av = ap[k];
            areg[i][k] = av;
            part[k] += hv * av;
        }
    }
#pragma unroll
    for (int k = 0; k < 16; ++k) {
        float v = part[k];
#pragma unroll
        for (int off = 32; off > 0; off >>= 1) v += __shfl_down(v, off);
        if (lane == 0) red2[wave * 16 + k] = v;
    }
    __syncthreads();
    float w[16];
    float mx = -1e30f;
#pragma unroll
    for (int k = 0; k < 16; ++k) {
        float s = (red2[k] + red2[16 + k] + red2[32 + k] + red2[48 + k]) * 0.03125f;
        w[k] = s;
        mx = fmaxf(mx, s);
    }
    float sum = 0.f;
#pragma unroll
    for (int k = 0; k < 16; ++k) {
        w[k] = expf(w[k] - mx);
        sum += w[k];
    }
    float inv = 1.0f / sum;
#pragma unroll
    for (int k = 0; k < 16; ++k) w[k] *= inv;
#pragma unroll
    for (int i = 0; i < 4; ++i) {
        float s = 0.f;
#pragma unroll
        for (int k = 0; k < 16; ++k) s += areg[i][k] * w[k];
        ash[tid + i * 256] = s;
    }
}

__device__ __forceinline__ void write_state_frags(unsigned short* __restrict__ Af,
                                                  const float* __restrict__ x,
                                                  const float* hsh, const float* ash,
                                                  int n, int tnext, int tid) {
    if (tid >= 128) return;
    int k8 = tid * 8;
    float v[8];
#pragma unroll
    for (int i = 0; i < 8; ++i) v[i] = hsh[k8 + i];
    write_frag8(Af, n, 1024 + k8, v);
#pragma unroll
    for (int i = 0; i < 8; ++i) v[i] = ash[k8 + i];
    write_frag8(Af, n, 2048 + k8, v);
    if (tnext < TT) {
        const float4* xp = reinterpret_cast<const float4*>(x + ((size_t)n * TT + tnext) * DD + k8);
        float4 x0 = xp[0], x1 = xp[1];
        v[0] = x0.x; v[1] = x0.y; v[2] = x0.z; v[3] = x0.w;
        v[4] = x1.x; v[5] = x1.y; v[6] = x1.z; v[7] = x1.w;
        write_frag8(Af, n, k8, v);
    }
}

// ---------------- init ----------------
__global__ __launch_bounds__(256) void initk(const float* __restrict__ A,
                                             const float* __restrict__ x,
                                             float* __restrict__ c,
                                             unsigned short* __restrict__ Af) {
    int n = blockIdx.x, tid = threadIdx.x;
    __shared__ float hsh[HH], ash[HH];
    __shared__ float red2[64];
#pragma unroll
    for (int i = 0; i < 4; ++i) {
        int hh = tid + i * 256;
        const float* ap = A + ((size_t)n * HH + hh) * 16;
        float s = 0.f;
#pragma unroll
        for (int k = 0; k < 16; ++k) s += ap[k];
        s *= (1.0f / 16.0f);
        c[(size_t)n * HH + hh] = s;
        hsh[hh] = s;
    }
    __syncthreads();
    attn_phase(A, n, tid, hsh, ash, red2);
    __syncthreads();
    write_state_frags(Af, x, hsh, ash, n, 0, tid);
}

// ---------------- MFMA GEMM: 32x32x16, fragment-direct, depth-4 reg pipeline, no LDS ----------------
#define DEPTH 4
#define KTPB 48   // kt16 per block (z splits 192 into 4)

#define LOADB(slot, kt)                                                                        \
    {                                                                                          \
        _Pragma("unroll") for (int lvl = 0; lvl < 2; ++lvl) {                                  \
            _Pragma("unroll") for (int mi = 0; mi < 2; ++mi)                                   \
                FA[slot][lvl][mi] = *reinterpret_cast<const uint4*>(pa[lvl][mi] + (size_t)(kt) * 512); \
            FB[slot][lvl] = *reinterpret_cast<const uint4*>(pb[lvl] + (size_t)(kt) * 512);     \
        }                                                                                      \
    }

__global__ __launch_bounds__(256, 2) void gemm_mfma(const unsigned short* __restrict__ Af,
                                                    const unsigned short* __restrict__ Bf,
                                                    float* __restrict__ apart) {
    int tid = threadIdx.x;
    int l = tid & 63, w = tid >> 6;       // 4 waves: 2wm x 2wn
    int wm = w & 1, wn = w >> 1;
    int bid = blockIdx.x;
    int id = (bid & 7) * 64 + (bid >> 3); // XCD-chunked bijective swizzle (512 % 8 == 0)
    int rowb = id & 1, colb = (id >> 1) & 63, z = id >> 7;
    int kt0 = z * KTPB;

    const unsigned short* pa[2][2];
    const unsigned short* pb[2];
#pragma unroll
    for (int lvl = 0; lvl < 2; ++lvl) {
#pragma unroll
        for (int mi = 0; mi < 2; ++mi)
            pa[lvl][mi] = Af + aoff(lvl, rowb * 4 + wm * 2 + mi, kt0, l);
        pb[lvl] = Bf + boff(lvl, colb * 2 + wn, kt0, l);
    }

    f32x16 accH[2] = {};
    f32x16 accM[2] = {};
    uint4 FA[DEPTH][2][2];
    uint4 FB[DEPTH][2];

    LOADB(0, 0)
    LOADB(1, 1)
    LOADB(2, 2)

#pragma unroll 4
    for (int kt = 0; kt < KTPB; ++kt) {
        int pf = (kt + 3 < KTPB) ? kt + 3 : KTPB - 1;
        LOADB((kt + 3) & 3, pf)
        int s = kt & 3;
        f16x8 b0 = __builtin_bit_cast(f16x8, FB[s][0]);
        f16x8 b1 = __builtin_bit_cast(f16x8, FB[s][1]);
#pragma unroll
        for (int mi = 0; mi < 2; ++mi) {
            f16x8 a0 = __builtin_bit_cast(f16x8, FA[s][0][mi]);
            f16x8 a1 = __builtin_bit_cast(f16x8, FA[s][1][mi]);
            accH[mi] = __builtin_amdgcn_mfma_f32_32x32x16_f16(a0, b0, accH[mi], 0, 0, 0);
            accM[mi] = __builtin_amdgcn_mfma_f32_32x32x16_f16(a0, b1, accM[mi], 0, 0, 0);
            accM[mi] = __builtin_amdgcn_mfma_f32_32x32x16_f16(a1, b0, accM[mi], 0, 0, 0);
        }
    }

    // epilogue: combine hi + mid/2048; C/D layout: col=l&31, row=(r&3)+8*(r>>2)+4*(l>>5)
    float* plane = apart + (size_t)z * P1;
    int col = colb * 64 + wn * 32 + (l & 31);
    int rb0 = rowb * 128 + wm * 64 + (l >> 5) * 4;
#pragma unroll
    for (int mi = 0; mi < 2; ++mi) {
        int rbase = rb0 + mi * 32;
#pragma unroll
        for (int r = 0; r < 16; ++r) {
            int row = rbase + (r & 3) + 8 * (r >> 2);
            plane[(size_t)row * FOURH + col] = accH[mi][r] + accM[mi][r] * INV_SPLIT;
        }
    }
}

// ---------------- pointwise: gates + LSTM + attn + frag writes ----------------
__global__ __launch_bounds__(256) void pointwise(const float* __restrict__ apart,
                                                 const float* __restrict__ bias,
                                                 const float* __restrict__ A,
                                                 const float* __restrict__ x,
                                                 float* __restrict__ c,
                                                 float* __restrict__ out,
                                                 unsigned short* __restrict__ Af, int t) {
    int n = blockIdx.x, tid = threadIdx.x;
    __shared__ float hsh[HH], ash[HH];
    __shared__ float red2[64];
    const float* ap = apart + (size_t)n * FOURH;
#pragma unroll
    for (int i = 0; i < 4; ++i) {
        int hh = i * 256 + tid;
        float g4[4];
#pragma unroll
        for (int g = 0; g < 4; ++g) {
            int j = g * 1024 + hh;
            g4[g] = bias[j] + ap[j] + ap[(size_t)P1 + j] + ap[2 * (size_t)P1 + j] + ap[3 * (size_t)P1 + j];
        }
        float ig = 1.f / (1.f + expf(-g4[0]));
        float fg = 1.f / (1.f + expf(-g4[1]));
        float og = 1.f / (1.f + expf(-g4[2]));
        float gg = tanhf(g4[3]);
        float cn = fg * c[(size_t)n * HH + hh] + ig * gg;
        float hn = og * tanhf(cn);
        c[(size_t)n * HH + hh] = cn;
        out[((size_t)n * TT + t) * HH + hh] = hn;
        hsh[hh] = hn;
    }
    __syncthreads();
    attn_phase(A, n, tid, hsh, ash, red2);
    __syncthreads();
    write_state_frags(Af, x, hsh, ash, n, t + 1, tid);
}

extern "C" void kernel_launch(void* const* d_in, const int* in_sizes, int n_in,
                              void* d_out, int out_size, void* d_ws, size_t ws_size,
                              hipStream_t stream) {
    const float* x     = (const float*)d_in[0];
    const float* A     = (const float*)d_in[1];
    const float* Wx    = (const float*)d_in[2];
    const float* Wh    = (const float*)d_in[3];
    const float* Wattn = (const float*)d_in[4];
    const float* b     = (const float*)d_in[5];
    float* out = (float*)d_out;

    unsigned short* Bf = (unsigned short*)d_ws;        // 2*BF_LVL f16 = 50.3 MB
    unsigned short* Af = Bf + 2 * BF_LVL;              // 2*AF_LVL f16 = 3.1 MB
    float* apart = (float*)(Af + 2 * AF_LVL);          // 4 * P1 f32 = 16 MB
    float* c = apart + 4 * (size_t)P1;                 // 1 MB

    wsplit_kernel<<<dim3(KTOT / 32, FOURH / 32), 256, 0, stream>>>(Wx, Wh, Wattn, Bf);
    initk<<<NB, 256, 0, stream>>>(A, x, c, Af);

    for (int t = 0; t < TT; ++t) {
        gemm_mfma<<<512, 256, 0, stream>>>(Af, Bf, apart);
        pointwise<<<NB, 256, 0, stream>>>(apart, b, A, x, c, out, Af, t);
    }
}

// Round 6
// 2826.130 us; speedup vs baseline: 1.4145x; 1.0051x over previous
//
#include <hip/hip_runtime.h>
#include <math.h>

#define NB 256
#define TT 64
#define DD 1024
#define HH 1024
#define FOURH 4096
#define KTOT 3072
#define KT16 192                  // K-tiles of 16
#define P1 (NB * FOURH)           // one partial plane (f32 elems)

#define AF_LVL 786432ull          // 8 mt * 192 kt * 512
#define BF_LVL 12582912ull        // 128 ct * 192 kt * 512
#define SPLIT_SCALE 2048.0f
#define INV_SPLIT (1.0f / 2048.0f)

typedef _Float16 f16x8 __attribute__((ext_vector_type(8)));
typedef float f32x4 __attribute__((ext_vector_type(4)));
typedef float f32x16 __attribute__((ext_vector_type(16)));

__device__ __forceinline__ unsigned short f2h(float f) {
    _Float16 h = (_Float16)f;
    unsigned short u;
    __builtin_memcpy(&u, &h, 2);
    return u;
}
__device__ __forceinline__ float h2f(unsigned short u) {
    _Float16 h;
    __builtin_memcpy(&h, &u, 2);
    return (float)h;
}
// 2-way fp16 split; lo pre-scaled by 2^11 to stay out of subnormal range
__device__ __forceinline__ void split2(float f, unsigned short& hi, unsigned short& lo) {
    hi = f2h(f);
    lo = f2h((f - h2f(hi)) * SPLIT_SCALE);
}

// 32x32x16 fragment layout: lane l holds [row/col = l&31][k = kt*16 + (l>>5)*8 + 0..7]
__device__ __forceinline__ size_t aoff(int lvl, int mt, int kt, int lane) {
    return ((size_t)((lvl * 8 + mt) * KT16 + kt) * 64 + lane) * 8;
}
__device__ __forceinline__ size_t boff(int lvl, int ct, int kt, int lane) {
    return ((size_t)((lvl * 128 + ct) * KT16 + kt) * 64 + lane) * 8;
}

__device__ __forceinline__ void write_frag8(unsigned short* __restrict__ Af, int n, int k8, const float* v) {
    int mt = n >> 5, kt = k8 >> 4;
    int lane = (n & 31) + 32 * ((k8 >> 3) & 1);
    unsigned short s[8][2];
#pragma unroll
    for (int i = 0; i < 8; ++i) split2(v[i], s[i][0], s[i][1]);
#pragma unroll
    for (int lvl = 0; lvl < 2; ++lvl) {
        uint4 p;
        p.x = (unsigned)s[0][lvl] | ((unsigned)s[1][lvl] << 16);
        p.y = (unsigned)s[2][lvl] | ((unsigned)s[3][lvl] << 16);
        p.z = (unsigned)s[4][lvl] | ((unsigned)s[5][lvl] << 16);
        p.w = (unsigned)s[6][lvl] | ((unsigned)s[7][lvl] << 16);
        *reinterpret_cast<uint4*>(Af + aoff(lvl, mt, kt, lane)) = p;
    }
}

// ---------------- weight split: W[k][j] f32 -> B-fragment order (2-level f16) ----------------
__global__ __launch_bounds__(256) void wsplit_kernel(const float* __restrict__ Wx,
                                                     const float* __restrict__ Wh,
                                                     const float* __restrict__ Wattn,
                                                     unsigned short* __restrict__ Bf) {
    __shared__ float tile[32][33];
    int k0 = blockIdx.x * 32, j0 = blockIdx.y * 32;
    int t = threadIdx.x;
    int rl = t >> 3, c4 = (t & 7) * 4;
    int seg = k0 >> 10;
    const float* W = (seg == 0) ? Wx : (seg == 1) ? Wh : Wattn;
    const float4 v = *reinterpret_cast<const float4*>(W + (size_t)((k0 & 1023) + rl) * FOURH + j0 + c4);
    tile[rl][c4 + 0] = v.x; tile[rl][c4 + 1] = v.y; tile[rl][c4 + 2] = v.z; tile[rl][c4 + 3] = v.w;
    __syncthreads();
    int jl = t >> 3, k4 = (t & 7) * 4;
    unsigned short s[4][2];
#pragma unroll
    for (int i = 0; i < 4; ++i) split2(tile[k4 + i][jl], s[i][0], s[i][1]);
    int j = j0 + jl;
    int kg = k0 + k4;
    int ct = j >> 5, kt = kg >> 4;
    int lane = (j & 31) + 32 * ((kg >> 3) & 1);
    int sub = kg & 7;   // 0 or 4
#pragma unroll
    for (int lvl = 0; lvl < 2; ++lvl) {
        uint2 p;
        p.x = (unsigned)s[0][lvl] | ((unsigned)s[1][lvl] << 16);
        p.y = (unsigned)s[2][lvl] | ((unsigned)s[3][lvl] << 16);
        *reinterpret_cast<uint2*>(Bf + boff(lvl, ct, kt, lane) + sub) = p;
    }
}

// ---------------- shared device phases (512 threads) ----------------
__device__ __forceinline__ void attn_phase(const float* __restrict__ A, int n, int tid,
                                           const float* hsh, float* ash, float* red2) {
    int lane = tid & 63, wave = tid >> 6;   // 8 waves
    const float* An = A + (size_t)n * HH * 16;
    float areg[2][16];
    float part[16];
#pragma unroll
    for (int k = 0; k < 16; ++k) part[k] = 0.f;
#pragma unroll
    for (int i = 0; i < 2; ++i) {
        int hh = tid + i * 512;
        float hv = hsh[hh];
        const float* ap = An + (size_t)hh * 16;
#pragma unroll
        for (int k = 0; k < 16; ++k) {
            float av = ap[k];
            areg[i][k] = av;
            part[k] += hv * av;
        }
    }
#pragma unroll
    for (int k = 0; k < 16; ++k) {
        float v = part[k];
#pragma unroll
        for (int off = 32; off > 0; off >>= 1) v += __shfl_down(v, off);
        if (lane == 0) red2[wave * 16 + k] = v;
    }
    __syncthreads();
    float w[16];
    float mx = -1e30f;
#pragma unroll
    for (int k = 0; k < 16; ++k) {
        float s = 0.f;
#pragma unroll
        for (int q = 0; q < 8; ++q) s += red2[q * 16 + k];
        s *= 0.03125f;
        w[k] = s;
        mx = fmaxf(mx, s);
    }
    float sum = 0.f;
#pragma unroll
    for (int k = 0; k < 16; ++k) {
        w[k] = expf(w[k] - mx);
        sum += w[k];
    }
    float inv = 1.0f / sum;
#pragma unroll
    for (int k = 0; k < 16; ++k) w[k] *= inv;
#pragma unroll
    for (int i = 0; i < 2; ++i) {
        float s = 0.f;
#pragma unroll
        for (int k = 0; k < 16; ++k) s += areg[i][k] * w[k];
        ash[tid + i * 512] = s;
    }
}

__device__ __forceinline__ void write_state_frags(unsigned short* __restrict__ Af,
                                                  const float* __restrict__ x,
                                                  const float* hsh, const float* ash,
                                                  int n, int tnext, int tid) {
    if (tid >= 128) return;
    int k8 = tid * 8;
    float v[8];
#pragma unroll
    for (int i = 0; i < 8; ++i) v[i] = hsh[k8 + i];
    write_frag8(Af, n, 1024 + k8, v);
#pragma unroll
    for (int i = 0; i < 8; ++i) v[i] = ash[k8 + i];
    write_frag8(Af, n, 2048 + k8, v);
    if (tnext < TT) {
        const float4* xp = reinterpret_cast<const float4*>(x + ((size_t)n * TT + tnext) * DD + k8);
        float4 x0 = xp[0], x1 = xp[1];
        v[0] = x0.x; v[1] = x0.y; v[2] = x0.z; v[3] = x0.w;
        v[4] = x1.x; v[5] = x1.y; v[6] = x1.z; v[7] = x1.w;
        write_frag8(Af, n, k8, v);
    }
}

// ---------------- init ----------------
__global__ __launch_bounds__(512) void initk(const float* __restrict__ A,
                                             const float* __restrict__ x,
                                             float* __restrict__ c,
                                             unsigned short* __restrict__ Af) {
    int n = blockIdx.x, tid = threadIdx.x;
    __shared__ float hsh[HH], ash[HH];
    __shared__ float red2[128];
#pragma unroll
    for (int i = 0; i < 2; ++i) {
        int hh = tid + i * 512;
        const float* ap = A + ((size_t)n * HH + hh) * 16;
        float s = 0.f;
#pragma unroll
        for (int k = 0; k < 16; ++k) s += ap[k];
        s *= (1.0f / 16.0f);
        c[(size_t)n * HH + hh] = s;
        hsh[hh] = s;
    }
    __syncthreads();
    attn_phase(A, n, tid, hsh, ash, red2);
    __syncthreads();
    write_state_frags(Af, x, hsh, ash, n, 0, tid);
}

// ---------------- MFMA GEMM: M=256 x N=64 x z4 tiles; B read exactly once ----------------
#define DEPTH 4
#define KTPB 48   // kt16 per block (z splits 192 into 4)

#define LOADB(slot, kt)                                                                        \
    {                                                                                          \
        _Pragma("unroll") for (int lvl = 0; lvl < 2; ++lvl) {                                  \
            _Pragma("unroll") for (int mi = 0; mi < 2; ++mi)                                   \
                FA[slot][lvl][mi] = *reinterpret_cast<const uint4*>(pa[lvl][mi] + (size_t)(kt) * 512); \
            FB[slot][lvl] = *reinterpret_cast<const uint4*>(pb[lvl] + (size_t)(kt) * 512);     \
        }                                                                                      \
    }

__global__ __launch_bounds__(512, 2) void gemm_mfma(const unsigned short* __restrict__ Af,
                                                    const unsigned short* __restrict__ Bf,
                                                    float* __restrict__ apart) {
    int tid = threadIdx.x;
    int l = tid & 63, w = tid >> 6;       // 8 waves: 4 wm x 2 wn
    int wm = w & 3, wn = w >> 2;
    int bid = blockIdx.x;
    int id = (bid & 7) * 32 + (bid >> 3); // XCD-chunked bijective swizzle (256 % 8 == 0)
    int colb = id & 63, z = id >> 6;      // same-z blocks land on 2 adjacent XCDs
    int kt0 = z * KTPB;

    const unsigned short* pa[2][2];
    const unsigned short* pb[2];
#pragma unroll
    for (int lvl = 0; lvl < 2; ++lvl) {
#pragma unroll
        for (int mi = 0; mi < 2; ++mi)
            pa[lvl][mi] = Af + aoff(lvl, wm * 2 + mi, kt0, l);
        pb[lvl] = Bf + boff(lvl, colb * 2 + wn, kt0, l);
    }

    f32x16 accH[2] = {};
    f32x16 accM[2] = {};
    uint4 FA[DEPTH][2][2];
    uint4 FB[DEPTH][2];

    LOADB(0, 0)
    LOADB(1, 1)
    LOADB(2, 2)

#pragma unroll 4
    for (int kt = 0; kt < KTPB; ++kt) {
        int pf = (kt + 3 < KTPB) ? kt + 3 : KTPB - 1;
        LOADB((kt + 3) & 3, pf)
        int s = kt & 3;
        f16x8 b0 = __builtin_bit_cast(f16x8, FB[s][0]);
        f16x8 b1 = __builtin_bit_cast(f16x8, FB[s][1]);
#pragma unroll
        for (int mi = 0; mi < 2; ++mi) {
            f16x8 a0 = __builtin_bit_cast(f16x8, FA[s][0][mi]);
            f16x8 a1 = __builtin_bit_cast(f16x8, FA[s][1][mi]);
            accH[mi] = __builtin_amdgcn_mfma_f32_32x32x16_f16(a0, b0, accH[mi], 0, 0, 0);
            accM[mi] = __builtin_amdgcn_mfma_f32_32x32x16_f16(a0, b1, accM[mi], 0, 0, 0);
            accM[mi] = __builtin_amdgcn_mfma_f32_32x32x16_f16(a1, b0, accM[mi], 0, 0, 0);
        }
    }

    // epilogue: combine hi + mid/2048; C/D layout: col=l&31, row=(r&3)+8*(r>>2)+4*(l>>5)
    float* plane = apart + (size_t)z * P1;
    int col = colb * 64 + wn * 32 + (l & 31);
#pragma unroll
    for (int mi = 0; mi < 2; ++mi) {
        int rbase = (wm * 2 + mi) * 32 + (l >> 5) * 4;
#pragma unroll
        for (int r = 0; r < 16; ++r) {
            int row = rbase + (r & 3) + 8 * (r >> 2);
            plane[(size_t)row * FOURH + col] = accH[mi][r] + accM[mi][r] * INV_SPLIT;
        }
    }
}

// ---------------- pointwise: gates + LSTM + attn + frag writes (512 thr) ----------------
__global__ __launch_bounds__(512) void pointwise(const float* __restrict__ apart,
                                                 const float* __restrict__ bias,
                                                 const float* __restrict__ A,
                                                 const float* __restrict__ x,
                                                 float* __restrict__ c,
                                                 float* __restrict__ out,
                                                 unsigned short* __restrict__ Af, int t) {
    int n = blockIdx.x, tid = threadIdx.x;
    __shared__ float hsh[HH], ash[HH];
    __shared__ float red2[128];
    const float* ap = apart + (size_t)n * FOURH;
#pragma unroll
    for (int i = 0; i < 2; ++i) {
        int hh = i * 512 + tid;
        float g4[4];
#pragma unroll
        for (int g = 0; g < 4; ++g) {
            int j = g * 1024 + hh;
            g4[g] = bias[j] + ap[j] + ap[(size_t)P1 + j] + ap[2 * (size_t)P1 + j] + ap[3 * (size_t)P1 + j];
        }
        float ig = 1.f / (1.f + expf(-g4[0]));
        float fg = 1.f / (1.f + expf(-g4[1]));
        float og = 1.f / (1.f + expf(-g4[2]));
        float gg = tanhf(g4[3]);
        float cn = fg * c[(size_t)n * HH + hh] + ig * gg;
        float hn = og * tanhf(cn);
        c[(size_t)n * HH + hh] = cn;
        out[((size_t)n * TT + t) * HH + hh] = hn;
        hsh[hh] = hn;
    }
    __syncthreads();
    attn_phase(A, n, tid, hsh, ash, red2);
    __syncthreads();
    write_state_frags(Af, x, hsh, ash, n, t + 1, tid);
}

extern "C" void kernel_launch(void* const* d_in, const int* in_sizes, int n_in,
                              void* d_out, int out_size, void* d_ws, size_t ws_size,
                              hipStream_t stream) {
    const float* x     = (const float*)d_in[0];
    const float* A     = (const float*)d_in[1];
    const float* Wx    = (const float*)d_in[2];
    const float* Wh    = (const float*)d_in[3];
    const float* Wattn = (const float*)d_in[4];
    const float* b     = (const float*)d_in[5];
    float* out = (float*)d_out;

    unsigned short* Bf = (unsigned short*)d_ws;        // 2*BF_LVL f16 = 50.3 MB
    unsigned short* Af = Bf + 2 * BF_LVL;              // 2*AF_LVL f16 = 3.1 MB
    float* apart = (float*)(Af + 2 * AF_LVL);          // 4 * P1 f32 = 16 MB
    float* c = apart + 4 * (size_t)P1;                 // 1 MB

    wsplit_kernel<<<dim3(KTOT / 32, FOURH / 32), 256, 0, stream>>>(Wx, Wh, Wattn, Bf);
    initk<<<NB, 512, 0, stream>>>(A, x, c, Af);

    for (int t = 0; t < TT; ++t) {
        gemm_mfma<<<256, 512, 0, stream>>>(Af, Bf, apart);
        pointwise<<<NB, 512, 0, stream>>>(apart, b, A, x, c, out, Af, t);
    }
}